// Round 1
// baseline (4237.378 us; speedup 1.0000x reference)
//
#include <hip/hip_runtime.h>
#include <hip/hip_bf16.h>
#include <stdint.h>

constexpr int TK  = 4096;   // B*S tokens
constexpr int DIMC = 1024;
constexpr int DFFC = 4096;
constexpr int VOC = 32000;
constexpr int NL  = 3;

typedef __attribute__((ext_vector_type(8))) short bf16x8;
typedef __attribute__((ext_vector_type(4))) float f32x4;

__device__ __forceinline__ unsigned short f2bf(float f) {
  unsigned int u = __float_as_uint(f);
  u += 0x7FFF + ((u >> 16) & 1);           // RNE; inputs are finite
  return (unsigned short)(u >> 16);
}

__device__ __forceinline__ float gelu_f(float x) {
  float x3 = x * x * x;
  return 0.5f * x * (1.0f + tanhf(0.7978845608028654f * (x + 0.044715f * x3)));
}

// ---------------- init: gather embeddings, reset per-call state ----------------
__global__ __launch_bounds__(256) void k_init(const int* __restrict__ x,
    const float* __restrict__ emb, float* __restrict__ h,
    int* __restrict__ active, int* __restrict__ cnts) {
  const int t = blockIdx.x, tid = threadIdx.x;
  if (t == 0 && tid < 16) cnts[tid] = 0;
  if (tid == 0) active[t] = 1;
  const int tok = x[t];
  ((float4*)(h + (size_t)t * DIMC))[tid] =
      ((const float4*)(emb + (size_t)tok * DIMC))[tid];
}

// ---------------- layernorm (two-pass, f32) ----------------
__global__ __launch_bounds__(256) void k_ln(const float* __restrict__ h,
    const float* __restrict__ g, const float* __restrict__ b,
    float* __restrict__ hn) {
  const int t = blockIdx.x, tid = threadIdx.x;
  const int lane = tid & 63, wid = tid >> 6;
  __shared__ float sm[4];
  float4 v = ((const float4*)(h + (size_t)t * DIMC))[tid];
  float s = v.x + v.y + v.z + v.w;
#pragma unroll
  for (int o = 32; o; o >>= 1) s += __shfl_down(s, o);
  if (lane == 0) sm[wid] = s;
  __syncthreads();
  const float mean = (sm[0] + sm[1] + sm[2] + sm[3]) * (1.0f / DIMC);
  __syncthreads();
  float4 d;
  d.x = v.x - mean; d.y = v.y - mean; d.z = v.z - mean; d.w = v.w - mean;
  float q = d.x * d.x + d.y * d.y + d.z * d.z + d.w * d.w;
#pragma unroll
  for (int o = 32; o; o >>= 1) q += __shfl_down(q, o);
  if (lane == 0) sm[wid] = q;
  __syncthreads();
  const float var = (sm[0] + sm[1] + sm[2] + sm[3]) * (1.0f / DIMC);
  const float rstd = 1.0f / sqrtf(var + 1e-5f);
  float4 gg = ((const float4*)g)[tid];
  float4 bb = ((const float4*)b)[tid];
  float4 o4;
  o4.x = d.x * rstd * gg.x + bb.x;
  o4.y = d.y * rstd * gg.y + bb.y;
  o4.z = d.z * rstd * gg.z + bb.z;
  o4.w = d.w * rstd * gg.w + bb.w;
  ((float4*)(hn + (size_t)t * DIMC))[tid] = o4;
}

// ---------------- f32 tiled GEMM: C = epi(A@B + bias [, +resid]) ----------------
// EPI==0: gelu (gemm1).  EPI==1: + resid (gemm2, resid = h).
template<int BM, int EPI>
__global__ __launch_bounds__(256) void k_gemm(
    const float* __restrict__ A, const float* __restrict__ B,
    const float* __restrict__ bias, const float* __restrict__ resid,
    float* __restrict__ C, int M, int N, int K)
{
  constexpr int BN = 128, BK = 8;
  constexpr int JM = BM / 16, JN = 8;
  __shared__ __align__(16) float As[2][BK][BM];
  __shared__ __align__(16) float Bs[2][BK][BN];
  const int tid = threadIdx.x;
  const int m0 = blockIdx.x * BM, n0 = blockIdx.y * BN;
  const int tm = (tid >> 4) * JM, tn = (tid & 15) * JN;
  float acc[JM][JN] = {};

  const int ar = (BM == 128) ? (tid >> 1) : (tid >> 2);
  const int ak = (BM == 128) ? ((tid & 1) * 4) : ((tid & 3) * 2);
  const int bk = tid >> 5, bn = (tid & 31) * 4;
  const float* Ag = A + (size_t)(m0 + ar) * K + ak;
  const float* Bg = B + (size_t)bk * N + n0 + bn;

  float4 va, vb;
  if constexpr (BM == 128) va = *(const float4*)(Ag);
  else { float2 t2 = *(const float2*)(Ag); va.x = t2.x; va.y = t2.y; va.z = 0; va.w = 0; }
  vb = *(const float4*)(Bg);

  auto writeA = [&](int buf, const float4& w) {
    As[buf][ak + 0][ar] = w.x;
    As[buf][ak + 1][ar] = w.y;
    if constexpr (BM == 128) {
      As[buf][ak + 2][ar] = w.z;
      As[buf][ak + 3][ar] = w.w;
    }
  };
  writeA(0, va);
  *(float4*)&Bs[0][bk][bn] = vb;
  __syncthreads();

  const int NT = K / BK;
  for (int kt = 0; kt < NT; ++kt) {
    const int buf = kt & 1;
    float4 na, nb;
    if (kt + 1 < NT) {
      if constexpr (BM == 128) na = *(const float4*)(Ag + (kt + 1) * BK);
      else { float2 t2 = *(const float2*)(Ag + (kt + 1) * BK); na.x = t2.x; na.y = t2.y; na.z = 0; na.w = 0; }
      nb = *(const float4*)(Bg + (size_t)(kt + 1) * BK * N);
    }
#pragma unroll
    for (int k = 0; k < BK; ++k) {
      float a[JM], b[JN];
      *(float4*)&a[0] = *(float4*)&As[buf][k][tm];
      if constexpr (BM == 128) *(float4*)&a[4] = *(float4*)&As[buf][k][tm + 4];
      *(float4*)&b[0] = *(float4*)&Bs[buf][k][tn];
      *(float4*)&b[4] = *(float4*)&Bs[buf][k][tn + 4];
#pragma unroll
      for (int i = 0; i < JM; ++i)
#pragma unroll
        for (int j = 0; j < JN; ++j)
          acc[i][j] += a[i] * b[j];
    }
    if (kt + 1 < NT) {
      writeA(buf ^ 1, na);
      *(float4*)&Bs[buf ^ 1][bk][bn] = nb;
      __syncthreads();
    }
  }

  float bcol[JN];
#pragma unroll
  for (int j = 0; j < JN; ++j) bcol[j] = bias[n0 + tn + j];
#pragma unroll
  for (int i = 0; i < JM; ++i) {
    const int m = m0 + tm + i;
    float* crow = C + (size_t)m * N + n0 + tn;
#pragma unroll
    for (int j = 0; j < JN; j += 4) {
      float4 o;
      o.x = acc[i][j + 0] + bcol[j + 0];
      o.y = acc[i][j + 1] + bcol[j + 1];
      o.z = acc[i][j + 2] + bcol[j + 2];
      o.w = acc[i][j + 3] + bcol[j + 3];
      if constexpr (EPI == 0) {
        o.x = gelu_f(o.x); o.y = gelu_f(o.y); o.z = gelu_f(o.z); o.w = gelu_f(o.w);
      } else {
        float4 r = *(const float4*)(resid + (size_t)m * N + n0 + tn + j);
        o.x += r.x; o.y += r.y; o.z += r.z; o.w += r.w;
      }
      *(float4*)(crow + j) = o;
    }
  }
}

// ---------------- decide: cos, take, compact exits to bf16, carry h forward ----------------
__global__ __launch_bounds__(256) void k_decide(
    float* __restrict__ h, const float* __restrict__ hout,
    int* __restrict__ active, int* __restrict__ cnts,
    int* __restrict__ exit_idx, unsigned short* __restrict__ hexit,
    int stage)
{
  const int t = blockIdx.x, tid = threadIdx.x;
  if (!active[t]) return;
  const int lane = tid & 63, wid = tid >> 6;
  __shared__ float sm[12];
  __shared__ int sif[2];
  float4 a = ((const float4*)(h + (size_t)t * DIMC))[tid];
  float4 o = ((const float4*)(hout + (size_t)t * DIMC))[tid];
  float hh = a.x * a.x + a.y * a.y + a.z * a.z + a.w * a.w;
  float ho = a.x * o.x + a.y * o.y + a.z * o.z + a.w * o.w;
  float oo = o.x * o.x + o.y * o.y + o.z * o.z + o.w * o.w;
#pragma unroll
  for (int off = 32; off; off >>= 1) {
    hh += __shfl_down(hh, off);
    ho += __shfl_down(ho, off);
    oo += __shfl_down(oo, off);
  }
  if (lane == 0) { sm[wid] = hh; sm[4 + wid] = ho; sm[8 + wid] = oo; }
  __syncthreads();
  if (tid == 0) {
    int take;
    if (stage == NL - 1) take = 1;
    else {
      const float HH = sm[0] + sm[1] + sm[2] + sm[3];
      const float HO = sm[4] + sm[5] + sm[6] + sm[7];
      const float OO = sm[8] + sm[9] + sm[10] + sm[11];
      const float cosv = HO / (sqrtf(HH) * sqrtf(OO) + 1e-8f);
      take = (cosv >= 0.98f) ? 1 : 0;
    }
    int pos = -1;
    if (take) {
      pos = atomicAdd(&cnts[stage], 1);
      exit_idx[pos] = t;
      active[t] = 0;
    }
    sif[0] = take; sif[1] = pos;
  }
  __syncthreads();
  if (sif[0]) {
    unsigned short* dst = hexit + (size_t)sif[1] * DIMC;
    ushort4 u;
    u.x = f2bf(o.x); u.y = f2bf(o.y); u.z = f2bf(o.z); u.w = f2bf(o.w);
    ((ushort4*)dst)[tid] = u;
  } else {
    ((float4*)(h + (size_t)t * DIMC))[tid] = o;
  }
}

// ---------------- logits: compacted bf16 MFMA GEMM, scatter-store rows ----------------
__global__ __launch_bounds__(256) void k_logits(
    const unsigned short* __restrict__ Ab,   // hexit bits [TK][DIMC]
    const float* __restrict__ Wout,          // [VOC][DIMC] f32
    const int* __restrict__ exit_idx,
    const int* __restrict__ pcnt,
    float* __restrict__ out)
{
  constexpr int BK = 32;
  const int cnt = *pcnt;
  const int rb = blockIdx.x, cb = blockIdx.y;
  if (rb * 128 >= cnt) return;
  __shared__ __align__(16) unsigned short As[2][128][40];
  __shared__ __align__(16) unsigned short Bs[2][128][40];
  const int tid = threadIdx.x;
  const int lane = tid & 63, wid = tid >> 6;
  const int wr = wid >> 1, wc = wid & 1;
  const int lr = lane & 15, lk = (lane >> 4) * 8;

  const int a_r = tid >> 2, a_c = (tid & 3) * 8;     // + q*64 rows (q<2)
  const int b_r = tid >> 3, b_c = (tid & 7) * 4;     // + q*32 rows (q<4)
  const unsigned short* Agp = Ab + (size_t)(rb * 128) * DIMC;
  const float* Bgp = Wout + (size_t)(cb * 128) * DIMC;

  f32x4 acc[4][4];
#pragma unroll
  for (int mi = 0; mi < 4; ++mi)
#pragma unroll
    for (int ni = 0; ni < 4; ++ni)
      acc[mi][ni] = (f32x4){0.f, 0.f, 0.f, 0.f};

  int4 va0, va1; float4 vb[4];
  auto loadAB = [&](int kt) {
    va0 = *(const int4*)(Agp + (size_t)a_r * DIMC + kt * BK + a_c);
    va1 = *(const int4*)(Agp + (size_t)(a_r + 64) * DIMC + kt * BK + a_c);
#pragma unroll
    for (int q = 0; q < 4; ++q)
      vb[q] = *(const float4*)(Bgp + (size_t)(b_r + 32 * q) * DIMC + kt * BK + b_c);
  };
  auto writeAB = [&](int buf) {
    *(int4*)&As[buf][a_r][a_c] = va0;
    *(int4*)&As[buf][a_r + 64][a_c] = va1;
#pragma unroll
    for (int q = 0; q < 4; ++q) {
      ushort4 u;
      u.x = f2bf(vb[q].x); u.y = f2bf(vb[q].y);
      u.z = f2bf(vb[q].z); u.w = f2bf(vb[q].w);
      *(ushort4*)&Bs[buf][b_r + 32 * q][b_c] = u;
    }
  };

  loadAB(0);
  writeAB(0);
  __syncthreads();
  const int NT = DIMC / BK;   // 32
  for (int kt = 0; kt < NT; ++kt) {
    const int buf = kt & 1;
    if (kt + 1 < NT) loadAB(kt + 1);
    bf16x8 aF[4], bF[4];
#pragma unroll
    for (int mi = 0; mi < 4; ++mi)
      aF[mi] = *(const bf16x8*)&As[buf][wr * 64 + mi * 16 + lr][lk];
#pragma unroll
    for (int ni = 0; ni < 4; ++ni)
      bF[ni] = *(const bf16x8*)&Bs[buf][wc * 64 + ni * 16 + lr][lk];
#pragma unroll
    for (int mi = 0; mi < 4; ++mi)
#pragma unroll
      for (int ni = 0; ni < 4; ++ni)
        acc[mi][ni] = __builtin_amdgcn_mfma_f32_16x16x32_bf16(aF[mi], bF[ni], acc[mi][ni], 0, 0, 0);
    if (kt + 1 < NT) {
      writeAB(buf ^ 1);
      __syncthreads();
    }
  }

  const int mvalid = cnt - rb * 128;
  const int rbase = (lane >> 4) * 4;
#pragma unroll
  for (int mi = 0; mi < 4; ++mi) {
#pragma unroll
    for (int r = 0; r < 4; ++r) {
      const int mrow = wr * 64 + mi * 16 + rbase + r;
      if (mrow < mvalid) {
        const int tok = exit_idx[rb * 128 + mrow];
        float* orow = out + (size_t)tok * VOC + cb * 128 + wc * 64 + lr;
#pragma unroll
        for (int ni = 0; ni < 4; ++ni)
          orow[ni * 16] = acc[mi][ni][r];
      }
    }
  }
}

// ---------------- host ----------------
extern "C" void kernel_launch(void* const* d_in, const int* in_sizes, int n_in,
                              void* d_out, int out_size, void* d_ws, size_t ws_size,
                              hipStream_t stream)
{
  const int*   x    = (const int*)d_in[0];
  const float* emb  = (const float*)d_in[1];
  const float* ln_g = (const float*)d_in[2];
  const float* ln_b = (const float*)d_in[3];
  const float* W1   = (const float*)d_in[4];
  const float* b1   = (const float*)d_in[5];
  const float* W2   = (const float*)d_in[6];
  const float* b2   = (const float*)d_in[7];
  const float* Wout = (const float*)d_in[8];
  float* out = (float*)d_out;

  char* p = (char*)d_ws;
  size_t off = 0;
  auto alloc = [&](size_t bytes) -> void* {
    void* r = p + off;
    off += (bytes + 255) & ~(size_t)255;
    return r;
  };
  float* h    = (float*)alloc((size_t)TK * DIMC * 4);
  float* hn   = (float*)alloc((size_t)TK * DIMC * 4);
  float* hout = (float*)alloc((size_t)TK * DIMC * 4);
  float* act  = (float*)alloc((size_t)TK * DFFC * 4);
  unsigned short* hexit = (unsigned short*)alloc((size_t)TK * DIMC * 2);
  int* exit_idx = (int*)alloc((size_t)TK * 4);
  int* active   = (int*)alloc((size_t)TK * 4);
  int* cnts     = (int*)alloc(64);

  k_init<<<TK, 256, 0, stream>>>(x, emb, h, active, cnts);
  for (int i = 0; i < NL; ++i) {
    k_ln<<<TK, 256, 0, stream>>>(h, ln_g + i * DIMC, ln_b + i * DIMC, hn);
    k_gemm<128, 0><<<dim3(TK / 128, DFFC / 128), 256, 0, stream>>>(
        hn, W1 + (size_t)i * DIMC * DFFC, b1 + (size_t)i * DFFC, nullptr, act,
        TK, DFFC, DIMC);
    k_gemm<64, 1><<<dim3(TK / 64, DIMC / 128), 256, 0, stream>>>(
        act, W2 + (size_t)i * DFFC * DIMC, b2 + (size_t)i * DIMC, h, hout,
        TK, DIMC, DFFC);
    k_decide<<<TK, 256, 0, stream>>>(h, hout, active, cnts, exit_idx, hexit, i);
    k_logits<<<dim3(TK / 128, VOC / 128), 256, 0, stream>>>(
        hexit, Wout, exit_idx, cnts + i, out);
  }
}